// Round 4
// baseline (2687.065 us; speedup 1.0000x reference)
//
#include <hip/hip_runtime.h>

// ---------------------------------------------------------------------------
// OseroNetworks, round 6: persistent grid-stride streaming with a software
// pipeline.
//
// Rounds 2-5 were all "one item per thread, load once, compute once, die":
// 8K resident waves fire their whole load burst at launch (~60 MB of instant
// demand), latency balloons to the queue depth, and no steady state forms --
// perf was invariant (150-165us) under occupancy 29<->73%, VGPR 28<->68,
// scalar vs LDS weights. Copy ubenches that reach 6.3 TB/s are persistent
// grid-stride loops; this version adopts that shape:
//
//  * 1024 blocks (4/CU, fully resident), each thread streams 16 slice-items
//    at machine stride; double-buffered item registers with an unroll-by-2
//    loop so buffer roles are static (no dynamic indexing -> no scratch).
//    Next item's 13 VMEM loads are issued BEFORE the current item's compute,
//    keeping loads in flight continuously (steady-state streaming).
//  * pairwise-K math: acc2 += W_f2[o][k] * x_f2[k], horizontal add at the
//    end. No {xv,xv} broadcast movs; weights stage into LDS as raw copies.
//  * runtime trip count -> loop stays rolled; __launch_bounds__(256,4).
// ---------------------------------------------------------------------------

typedef float f2 __attribute__((ext_vector_type(2)));

__device__ __forceinline__ f2 pk_fma(f2 a, f2 b, f2 c) {
    return __builtin_elementwise_fma(a, b, c);
}

struct SW {
    f2 eW1[50], eW2[50], cW1[50], cW2[50];   // 10-D layers, raw row-major f2
    f2 xW1[32], xW2[32];                     // 8-D layers
    f2 eW3[5],  cW3[5],  xW3[4];             // output rows
    float eb1[10], eb2[10], cb1[10], cb2[10];
    float xb1[8],  xb2[8];
};

// 3-layer MLP, pairwise-K accumulation. Returns un-biased (no b3) output.
template<int D>
__device__ __forceinline__ float mlp_pairK(const f2* xs,
                                           const f2* __restrict__ W1,
                                           const float* __restrict__ b1,
                                           const f2* __restrict__ W2,
                                           const float* __restrict__ b2,
                                           const f2* __restrict__ W3)
{
    constexpr int H = D / 2;
    float h1[D];
    #pragma unroll
    for (int o = 0; o < D; ++o) {
        f2 a = {b1[o], 0.0f};
        #pragma unroll
        for (int k = 0; k < H; ++k)
            a = pk_fma(W1[o * H + k], xs[k], a);
        h1[o] = fmaxf(a.x + a.y, 0.0f);
    }
    float h2[D];
    #pragma unroll
    for (int o = 0; o < D; ++o) {
        f2 a = {b2[o], 0.0f};
        #pragma unroll
        for (int k = 0; k < H; ++k)
            a = pk_fma(W2[o * H + k], (f2){h1[2 * k], h1[2 * k + 1]}, a);
        h2[o] = fmaxf(a.x + a.y, 0.0f);
    }
    f2 acc = {0.0f, 0.0f};
    #pragma unroll
    for (int k = 0; k < H; ++k)
        acc = pk_fma(W3[k], (f2){h2[2 * k], h2[2 * k + 1]}, acc);
    return acc.x + acc.y;
}

struct Item { f2 xe[5], xq[5], xc[4]; float cnv; };

__device__ __forceinline__ void load_item(Item& it, int g, int s,
        const float* __restrict__ edge, const float* __restrict__ corner,
        const float* __restrict__ cross_, const float* __restrict__ cn)
{
    const f2* pe = reinterpret_cast<const f2*>(edge)   + (size_t)g * 5;
    const f2* pq = reinterpret_cast<const f2*>(corner) + (size_t)g * 5;
    #pragma unroll
    for (int k = 0; k < 5; ++k) it.xe[k] = pe[k];
    #pragma unroll
    for (int k = 0; k < 5; ++k) it.xq[k] = pq[k];
    const float4* pc = reinterpret_cast<const float4*>(cross_) + (size_t)g * 2;
    const float4 v0 = pc[0], v1 = pc[1];
    it.xc[0] = (f2){v0.x, v0.y}; it.xc[1] = (f2){v0.z, v0.w};
    it.xc[2] = (f2){v1.x, v1.y}; it.xc[3] = (f2){v1.z, v1.w};
    it.cnv = (s == 0) ? cn[g >> 2] : 0.0f;
}

__device__ __forceinline__ void process_item(const Item& it, int g, int s,
        const SW& sw, float tail, float nw0, float nb0,
        float* __restrict__ out)
{
    float val = mlp_pairK<10>(it.xe, sw.eW1, sw.eb1, sw.eW2, sw.eb2, sw.eW3);
    val      += mlp_pairK<10>(it.xq, sw.cW1, sw.cb1, sw.cW2, sw.cb2, sw.cW3);
    val      += mlp_pairK<8> (it.xc, sw.xW1, sw.xb1, sw.xW2, sw.xb2, sw.xW3);
    val += __shfl_xor(val, 1, 4);
    val += __shfl_xor(val, 2, 4);
    if (s == 0)
        out[g >> 2] = val + tail + fmaf(it.cnv, nw0, nb0);
}

__global__ __launch_bounds__(256, 4)
void osero_kernel(const float* __restrict__ edge,
                  const float* __restrict__ cross_,
                  const float* __restrict__ corner,
                  const float* __restrict__ cn,
                  const float* __restrict__ eW1, const float* __restrict__ eb1,
                  const float* __restrict__ eW2, const float* __restrict__ eb2,
                  const float* __restrict__ eW3, const float* __restrict__ eb3,
                  const float* __restrict__ xW1, const float* __restrict__ xb1,
                  const float* __restrict__ xW2, const float* __restrict__ xb2,
                  const float* __restrict__ xW3, const float* __restrict__ xb3,
                  const float* __restrict__ cW1, const float* __restrict__ cb1,
                  const float* __restrict__ cW2, const float* __restrict__ cb2,
                  const float* __restrict__ cW3, const float* __restrict__ cb3,
                  const float* __restrict__ nW,  const float* __restrict__ nb,
                  float* __restrict__ out, int nthr)
{
    __shared__ SW sw;
    const int t  = threadIdx.x;
    const int g0 = blockIdx.x * 256 + t;
    const int gstride = gridDim.x * 256;
    const int s  = t & 3;
    const int iters = nthr / gstride;       // launcher guarantees divisibility

    // First item's loads go out before anything else (overlap with staging).
    Item A, B;
    load_item(A, g0, s, edge, corner, cross_, cn);

    // One-time weight staging: raw f2/float copies (no pair transform).
    if (t < 50) {
        sw.eW1[t] = reinterpret_cast<const f2*>(eW1)[t];
        sw.eW2[t] = reinterpret_cast<const f2*>(eW2)[t];
        sw.cW1[t] = reinterpret_cast<const f2*>(cW1)[t];
        sw.cW2[t] = reinterpret_cast<const f2*>(cW2)[t];
    } else if (t >= 64 && t < 96) {
        const int j = t - 64;
        sw.xW1[j] = reinterpret_cast<const f2*>(xW1)[j];
        sw.xW2[j] = reinterpret_cast<const f2*>(xW2)[j];
    } else if (t >= 128 && t < 138) {
        const int k = t - 128;
        sw.eb1[k] = eb1[k]; sw.eb2[k] = eb2[k];
        sw.cb1[k] = cb1[k]; sw.cb2[k] = cb2[k];
    } else if (t >= 160 && t < 165) {
        const int k = t - 160;
        sw.eW3[k] = reinterpret_cast<const f2*>(eW3)[k];
        sw.cW3[k] = reinterpret_cast<const f2*>(cW3)[k];
    } else if (t >= 192 && t < 200) {
        const int k = t - 192;
        sw.xb1[k] = xb1[k]; sw.xb2[k] = xb2[k];
    } else if (t >= 224 && t < 228) {
        const int k = t - 224;
        sw.xW3[k] = reinterpret_cast<const f2*>(xW3)[k];
    }
    const float tail = 4.0f * (eb3[0] + cb3[0] + xb3[0]);
    const float nw0 = nW[0], nb0 = nb[0];
    __syncthreads();

    // Steady-state stream: issue next item's loads, then compute current.
    int g = g0, it = 0;
    for (; it + 2 <= iters; it += 2) {
        load_item(B, g + gstride, s, edge, corner, cross_, cn);
        process_item(A, g, s, sw, tail, nw0, nb0, out);
        const int gpre = (it + 2 < iters) ? g + 2 * gstride : g0; // dummy on last
        load_item(A, gpre, s, edge, corner, cross_, cn);
        process_item(B, g + gstride, s, sw, tail, nw0, nb0, out);
        g += 2 * gstride;
    }
    if (it < iters)                          // odd trip-count tail
        process_item(A, g, s, sw, tail, nw0, nb0, out);
}

extern "C" void kernel_launch(void* const* d_in, const int* in_sizes, int n_in,
                              void* d_out, int out_size, void* d_ws, size_t ws_size,
                              hipStream_t stream) {
    const float* edge   = (const float*)d_in[0];
    const float* cross_ = (const float*)d_in[1];
    const float* corner = (const float*)d_in[2];
    const float* cn     = (const float*)d_in[3];
    const float* eW1 = (const float*)d_in[4];
    const float* eb1 = (const float*)d_in[5];
    const float* eW2 = (const float*)d_in[6];
    const float* eb2 = (const float*)d_in[7];
    const float* eW3 = (const float*)d_in[8];
    const float* eb3 = (const float*)d_in[9];
    const float* xW1 = (const float*)d_in[10];
    const float* xb1 = (const float*)d_in[11];
    const float* xW2 = (const float*)d_in[12];
    const float* xb2 = (const float*)d_in[13];
    const float* xW3 = (const float*)d_in[14];
    const float* xb3 = (const float*)d_in[15];
    const float* cW1 = (const float*)d_in[16];
    const float* cb1 = (const float*)d_in[17];
    const float* cW2 = (const float*)d_in[18];
    const float* cb2 = (const float*)d_in[19];
    const float* cW3 = (const float*)d_in[20];
    const float* cb3 = (const float*)d_in[21];
    const float* nW  = (const float*)d_in[22];
    const float* nb  = (const float*)d_in[23];

    const int nelem = in_sizes[3];          // cn is [B,1] -> B
    const int nthr  = nelem * 4;            // one slice-item per (element, slice)

    // 1024 persistent blocks (4/CU) when divisible; else 1 item/thread.
    int nblk = 1024;
    if (nthr % (1024 * 256) != 0) nblk = nthr / 256;

    osero_kernel<<<dim3(nblk), 256, 0, stream>>>(edge, cross_, corner, cn,
                                                 eW1, eb1, eW2, eb2, eW3, eb3,
                                                 xW1, xb1, xW2, xb2, xW3, xb3,
                                                 cW1, cb1, cW2, cb2, cW3, cb3,
                                                 nW, nb, (float*)d_out, nthr);
}